// Round 1
// 3748.659 us; speedup vs baseline: 2.0219x; 2.0219x over previous
//
#include <hip/hip_runtime.h>
#include <math.h>

#define Bq 64
#define Tq 512
#define Hq 1024
#define G4 4096
#define NBLK 256
#define NTHR 512

typedef __attribute__((ext_vector_type(8))) short short8;   // 8 bf16
typedef __attribute__((ext_vector_type(4))) float float4v;  // MFMA acc

static __device__ __forceinline__ short f2bf(float f) {
    union { float f; unsigned u; } c; c.f = f;
    unsigned r = (c.u + 0x7fffu + ((c.u >> 16) & 1u)) >> 16;  // RNE
    return (short)r;
}

static __device__ __forceinline__ short8 load_cvt8(const float* p) {
    const float4* q = (const float4*)p;  // 32B-aligned by construction
    float4 v0 = q[0], v1 = q[1];
    short8 r;
    r[0] = f2bf(v0.x); r[1] = f2bf(v0.y); r[2] = f2bf(v0.z); r[3] = f2bf(v0.w);
    r[4] = f2bf(v1.x); r[5] = f2bf(v1.y); r[6] = f2bf(v1.z); r[7] = f2bf(v1.w);
    return r;
}

// agent-scope relaxed atomic helpers (cache-bypass, coherent point; no fences)
static __device__ __forceinline__ unsigned aload_u(const unsigned* p) {
    return __hip_atomic_load(p, __ATOMIC_RELAXED, __HIP_MEMORY_SCOPE_AGENT);
}
static __device__ __forceinline__ void astore_u(unsigned* p, unsigned v) {
    __hip_atomic_store(p, v, __ATOMIC_RELAXED, __HIP_MEMORY_SCOPE_AGENT);
}
static __device__ __forceinline__ unsigned long long aload_u64(const unsigned long long* p) {
    return __hip_atomic_load(p, __ATOMIC_RELAXED, __HIP_MEMORY_SCOPE_AGENT);
}

// ---------------------------------------------------------------------------
// Persistent LSTM. Grid: 256 blocks (4 mc-groups x 64 jc) x 512 threads.
// The 4 mc-groups are INDEPENDENT recurrences: barrier is per-group (64 blocks).
// h is stored bf16 (identical numerics: consumer converted to bf16 anyway),
// moved via coalesced 8B relaxed-agent loads / packed 4B stores.
// x-MFMA for step t+1 runs in the poll shadow; out-store runs after the
// barrier (staged via LDS, issued by x-waves concurrently with next h-load).
// ---------------------------------------------------------------------------
__global__ __launch_bounds__(NTHR, 1) void lstm_persist(
        const float* __restrict__ x, const float* __restrict__ Wx,
        const float* __restrict__ Wh, const float* __restrict__ bias,
        float* __restrict__ out, unsigned short* __restrict__ h0b,
        unsigned short* __restrict__ h1b, unsigned* __restrict__ flags)
{
    __shared__ float part[8][16][68];   // stride 68: bank-conflict-free
    __shared__ float gtile[16][68];
    __shared__ float houtbuf[16][16];   // staged h (fp32) for deferred out-store
    __shared__ float sbias[64];

    const int tid  = threadIdx.x;
    const int w    = tid >> 6;
    const int lane = tid & 63;
    const int blk  = blockIdx.x;
    const int mc   = blk >> 6;    // 0..3   batch-row group (independent chains)
    const int jc   = blk & 63;    // 0..63  j group (16 j's)
    const int quad = lane >> 4;   // 0..3
    const int n    = lane & 15;   // MFMA row/col within tile
    const int gN   = n >> 2;      // gate index for B cols
    const int jl4  = n & 3;

    if (tid < 64) {
        int u = tid >> 4, nn = tid & 15;
        sbias[u * 16 + nn] = bias[(nn >> 2) * Hq + jc * 16 + u * 4 + (nn & 3)];
    }

    // ---- one-time: load B fragments (bf16) into registers -----------------
    // virtual K = [ h (0..1023) | x (1024..2047) ]; wave w owns [w*256, +256)
    short8 bs[4][8];  // [N-tile u][k-step s]
    const int kchunk = w * 256;
#pragma unroll
    for (int u = 0; u < 4; ++u) {
        const int col = gN * Hq + jc * 16 + u * 4 + jl4;
#pragma unroll
        for (int s = 0; s < 8; ++s) {
            const int kb = kchunk + s * 32 + quad * 8;
#pragma unroll
            for (int j = 0; j < 8; ++j) {
                const int kv = kb + j;
                float v = (kv < Hq) ? Wh[(size_t)kv * G4 + col]
                                    : Wx[(size_t)(kv - Hq) * G4 + col];
                bs[u][s][j] = f2bf(v);
            }
        }
    }

    float cstate = 0.f;          // cell state (threads 0..255)
    const int urow = tid >> 4;   // 0..15 (valid when tid<256)
    const int ujl  = tid & 15;

    const int m_g = mc * 16 + n;  // A row (batch) for this lane
    const float* xbase = x + (size_t)m_g * Tq * Hq +
                         ((w >= 4) ? (w - 4) * 256 + quad * 8 : 0);
    const size_t hoff = (size_t)m_g * Hq + (size_t)(w * 256) + quad * 8;  // shorts

    // x-projection partials for timestep tt -> part[w]   (waves 4..7)
    auto xstep = [&](int tt) {
        float4v a0 = {0,0,0,0}, a1 = {0,0,0,0}, a2 = {0,0,0,0}, a3 = {0,0,0,0};
        const float* ap = xbase + (size_t)tt * Hq;
#pragma unroll
        for (int s = 0; s < 8; ++s) {
            short8 a = load_cvt8(ap + s * 32);
            a0 = __builtin_amdgcn_mfma_f32_16x16x32_bf16(a, bs[0][s], a0, 0, 0, 0);
            a1 = __builtin_amdgcn_mfma_f32_16x16x32_bf16(a, bs[1][s], a1, 0, 0, 0);
            a2 = __builtin_amdgcn_mfma_f32_16x16x32_bf16(a, bs[2][s], a2, 0, 0, 0);
            a3 = __builtin_amdgcn_mfma_f32_16x16x32_bf16(a, bs[3][s], a3, 0, 0, 0);
        }
#pragma unroll
        for (int r = 0; r < 4; ++r) {
            part[w][quad * 4 + r][ 0 + n] = a0[r];
            part[w][quad * 4 + r][16 + n] = a1[r];
            part[w][quad * 4 + r][32 + n] = a2[r];
            part[w][quad * 4 + r][48 + n] = a3[r];
        }
    };

    // h-recurrence partials from bf16 h buffer -> part[w]   (waves 0..3)
    auto hstep = [&](const unsigned short* hb) {
        const unsigned long long* p = (const unsigned long long*)(hb + hoff);
        short8 afr[8];
#pragma unroll
        for (int s = 0; s < 8; ++s) {   // issue all 16 loads, then compute
            union { unsigned long long u[2]; short8 s8; } uu;
            uu.u[0] = aload_u64(p + s * 8);
            uu.u[1] = aload_u64(p + s * 8 + 1);
            afr[s] = uu.s8;
        }
        float4v a0 = {0,0,0,0}, a1 = {0,0,0,0}, a2 = {0,0,0,0}, a3 = {0,0,0,0};
#pragma unroll
        for (int s = 0; s < 8; ++s) {
            a0 = __builtin_amdgcn_mfma_f32_16x16x32_bf16(afr[s], bs[0][s], a0, 0, 0, 0);
            a1 = __builtin_amdgcn_mfma_f32_16x16x32_bf16(afr[s], bs[1][s], a1, 0, 0, 0);
            a2 = __builtin_amdgcn_mfma_f32_16x16x32_bf16(afr[s], bs[2][s], a2, 0, 0, 0);
            a3 = __builtin_amdgcn_mfma_f32_16x16x32_bf16(afr[s], bs[3][s], a3, 0, 0, 0);
        }
#pragma unroll
        for (int r = 0; r < 4; ++r) {
            part[w][quad * 4 + r][ 0 + n] = a0[r];
            part[w][quad * 4 + r][16 + n] = a1[r];
            part[w][quad * 4 + r][32 + n] = a2[r];
            part[w][quad * 4 + r][48 + n] = a3[r];
        }
    };

    // ---- prologue: x partials for t=0; zero h partials ---------------------
    if (w >= 4) {
        xstep(0);
    } else {
#pragma unroll
        for (int r = 0; r < 16; ++r) part[w][r][lane] = 0.f;
    }

    for (int t = 0; t < Tq; ++t) {
        __syncthreads();   // S1: part(t) complete (h from prev iter, x from prev iter)

        // reduce 8 partials -> gates (1024 values, 2 per thread)
#pragma unroll
        for (int e = 0; e < 2; ++e) {
            int idx = tid + e * NTHR;
            int rr = idx >> 6, cc = idx & 63;
            float s = part[0][rr][cc];
#pragma unroll
            for (int ww = 1; ww < 8; ++ww) s += part[ww][rr][cc];
            gtile[rr][cc] = s + sbias[cc];
        }
        __syncthreads();   // S2

        unsigned short* hw = (t & 1) ? h0b : h1b;  // buffer written this step
        if (tid < 256) {
            const int u = ujl >> 2, j4 = ujl & 3;
            float gi = gtile[urow][u * 16 +  0 + j4];
            float gf = gtile[urow][u * 16 +  4 + j4];
            float gg = gtile[urow][u * 16 +  8 + j4];
            float go = gtile[urow][u * 16 + 12 + j4];
            float i_ = 1.f / (1.f + __expf(-gi));
            float f_ = 1.f / (1.f + __expf(-gf));
            float g_ = tanhf(gg);
            float o_ = 1.f / (1.f + __expf(-go));
            cstate = f_ * cstate + i_ * g_;
            float hn = o_ * tanhf(cstate);
            houtbuf[urow][ujl] = hn;   // stage for deferred out-store
            // pack 2 neighboring bf16 into one u32 cache-bypass store
            unsigned hp = (unsigned)(unsigned short)f2bf(hn);
            unsigned up = __shfl_down(hp, 1);
            if (!(tid & 1)) {
                const int bg = mc * 16 + urow;
                astore_u((unsigned*)(hw + (size_t)bg * Hq + jc * 16 + ujl),
                         hp | (up << 16));
            }
        }
        __syncthreads();   // S3: all h stores acked at coherence point

        if (t + 1 < Tq) {
            if (tid == 0) astore_u(&flags[blk], (unsigned)(t + 1));
            // x-MFMA for t+1 overlaps the group barrier (waves 4..7)
            if (w >= 4) xstep(t + 1);
            // per-mc-group barrier: 64 flags, one load per lane (wave 0 only)
            if (w == 0) {
                const unsigned tgt = (unsigned)(t + 1);
                const unsigned* fb = flags + (mc << 6);
                for (;;) {
                    unsigned a0 = aload_u(&fb[lane]);
                    if (__all(a0 >= tgt)) break;
                }
            }
        }
        __syncthreads();   // S4: group advanced; h(t) visible everywhere

        if (w >= 4) {
            // deferred out-store (off critical path; overlaps next h-load)
            const int idx = tid - 256;              // 0..255
            const int r = idx >> 4, c = idx & 15;
            out[((size_t)(mc * 16 + r) * Tq + t) * Hq + jc * 16 + c] = houtbuf[r][c];
        } else if (t + 1 < Tq) {
            hstep(hw);     // h partials for t+1 -> part[w]
        }
    }
}

extern "C" void kernel_launch(void* const* d_in, const int* in_sizes, int n_in,
                              void* d_out, int out_size, void* d_ws, size_t ws_size,
                              hipStream_t stream) {
    const float* x    = (const float*)d_in[0];
    const float* Wx   = (const float*)d_in[1];
    const float* Wh   = (const float*)d_in[2];
    const float* bias = (const float*)d_in[3];
    float* out = (float*)d_out;

    // ws layout: flags[256] u32 (1 KB) | h0[64*1024] bf16 (128 KB) | h1 bf16 (128 KB)
    unsigned* flags = (unsigned*)d_ws;
    unsigned short* h0b = (unsigned short*)((char*)d_ws + 1024);
    unsigned short* h1b = h0b + Bq * Hq;

    // zero flags (h buffers never read at t=0; kernel skips the h-MFMA there)
    hipMemsetAsync(d_ws, 0, 1024, stream);

    void* args[] = {(void*)&x, (void*)&Wx, (void*)&Wh, (void*)&bias,
                    (void*)&out, (void*)&h0b, (void*)&h1b, (void*)&flags};
    hipLaunchCooperativeKernel((const void*)lstm_persist, dim3(NBLK), dim3(NTHR),
                               args, 0, stream);
}